// Round 1
// baseline (3192.177 us; speedup 1.0000x reference)
//
// MANN/NTM forward — R10: pin waves_per_eu(2,2) on mann_kernel.
// Theory: LDS (83KB) caps residency at 1 block/CU = 2 waves/EU, but the
// compiler register-targeted 4 waves/EU (VGPR_Count=128). PIPE4's w0..w3[8]
// float4 buffers alone are 128 VGPRs -> pipeline spilled/collapsed to scratch
// (WRITE_SIZE 37MB vs 0.5MB of true output). Pinning waves/EU to the real
// occupancy gives the allocator the 256-VGPR budget so the GEMV software
// pipeline actually lives in registers.
#include <hip/hip_runtime.h>
#include <math.h>

#define TB   100
#define BB   256
#define INF_ 784
#define HH   200
#define RR   4
#define NN   128
#define DD   40
#define NCLS 5
#define G4H  800   // 4*H
#define KAW  324   // 160 key + 160 add + 1 sigma + 3 pad
#define MST  44    // padded M row stride
#define NBAT 2     // batches per block
#define NBLK (BB / NBAT)

__device__ __forceinline__ float sigmoidf_(float x) { return 1.0f / (1.0f + expf(-x)); }

#define ADV(c, CC) { ++(c); if ((c) == (CC)) (c) = 0; }

// 4-slot rotating software pipeline (3 chunks of loads in flight ahead of FMA).
#define PIPE4(CC, OFS, LOADM, FMAM)                                     \
  {                                                                     \
    int chL = (OFS), chF = (OFS);                                       \
    LOADM(w0, chL); ADV(chL, CC); LOADM(w1, chL); ADV(chL, CC);         \
    LOADM(w2, chL); ADV(chL, CC);                                       \
    _Pragma("unroll 1")                                                 \
    for (int g = 0; g < ((CC) - 3) / 4; ++g) {                          \
      LOADM(w3, chL); ADV(chL, CC); FMAM(w0, chF); ADV(chF, CC);        \
      LOADM(w0, chL); ADV(chL, CC); FMAM(w1, chF); ADV(chF, CC);        \
      LOADM(w1, chL); ADV(chL, CC); FMAM(w2, chF); ADV(chF, CC);        \
      LOADM(w2, chL); ADV(chL, CC); FMAM(w3, chF); ADV(chF, CC);        \
    }                                                                   \
    {                                                                   \
      constexpr int REMX = (CC) - 3 - 4 * (((CC) - 3) / 4);             \
      if (REMX >= 1) { LOADM(w3, chL); ADV(chL, CC); }                  \
      FMAM(w0, chF); ADV(chF, CC);                                      \
      if (REMX >= 2) { LOADM(w0, chL); ADV(chL, CC); }                  \
      FMAM(w1, chF); ADV(chF, CC);                                      \
      if (REMX >= 3) { LOADM(w1, chL); ADV(chL, CC); }                  \
      FMAM(w2, chF); ADV(chF, CC);                                      \
      if (REMX >= 1) { FMAM(w3, chF); ADV(chF, CC); }                   \
      if (REMX >= 2) { FMAM(w0, chF); ADV(chF, CC); }                   \
      if (REMX >= 3) { FMAM(w1, chF); ADV(chF, CC); }                   \
    }                                                                   \
  }

// ---------------------------------------------------------------------------
// Prep: transpose weights into GEMV-friendly (k-major) layouts in workspace.
// ---------------------------------------------------------------------------
__global__ __launch_bounds__(256) void prep_kernel(
    const float* __restrict__ Whh, const float* __restrict__ Wrh,
    const float* __restrict__ Wkey, const float* __restrict__ Wadd,
    const float* __restrict__ Wsig, const float* __restrict__ bkey,
    const float* __restrict__ badd, const float* __restrict__ bsig,
    float* __restrict__ WhhT, float* __restrict__ WrhT,
    float* __restrict__ WkaT, float* __restrict__ bka)
{
  const int tid = blockIdx.x * 256 + threadIdx.x;
  if (tid < 160000) {            // Whh (800,200) -> WhhT (200,800)
    const int j = tid / 200, k = tid - j * 200;
    WhhT[k * G4H + j] = Whh[tid];
  }
  if (tid < 32000) {             // Wrh (200,160) -> WrhT (160,200)
    const int k = tid / 160, m = tid - k * 160;
    WrhT[m * HH + k] = Wrh[tid];
  }
  if (tid < 200 * KAW) {         // [Wkey(160,200)|Wadd(160,200)|Wsig(1,200)]^T
    const int k = tid / KAW, j = tid - k * KAW;
    float v = 0.0f;
    if (j < 160)       v = Wkey[j * HH + k];
    else if (j < 320)  v = Wadd[(j - 160) * HH + k];
    else if (j == 320) v = Wsig[k];
    WkaT[tid] = v;
  }
  if (tid < KAW) {
    float v = 0.0f;
    if (tid < 160)       v = bkey[tid];
    else if (tid < 320)  v = badd[tid - 160];
    else if (tid == 320) v = bsig[0];
    bka[tid] = v;
  }
}

// ---------------------------------------------------------------------------
// Big GEMM: G[m, j] = sum_k x[m,k]*Wih[j,k] + bih[j] + bhh[j]
// ---------------------------------------------------------------------------
__global__ __launch_bounds__(256) void gemm_in_kernel(
    const float* __restrict__ X, const float* __restrict__ Wih,
    const float* __restrict__ bih, const float* __restrict__ bhh,
    float* __restrict__ G)
{
  __shared__ float As[16 * 68];
  __shared__ float Bs[16 * 68];
  const int tid  = threadIdx.x;
  const int tx   = tid & 15, ty = tid >> 4;
  const int lrow = tid >> 2, lk = (tid & 3) * 4;
  const int n0 = blockIdx.x * 64;
  const int m0 = blockIdx.y * 64;
  const int jg = n0 + lrow;
  const float* Xp = X   + (size_t)(m0 + lrow) * INF_ + lk;
  const float* Wp = Wih + (size_t)jg * INF_ + lk;

  float acc[4][4];
#pragma unroll
  for (int i = 0; i < 4; ++i)
#pragma unroll
    for (int j = 0; j < 4; ++j) acc[i][j] = 0.f;

  for (int k0 = 0; k0 < INF_; k0 += 16) {
    const float4 a = *(const float4*)(Xp + k0);
    const float4 b = (jg < G4H) ? *(const float4*)(Wp + k0)
                                : make_float4(0.f, 0.f, 0.f, 0.f);
    __syncthreads();
    const float av[4] = {a.x, a.y, a.z, a.w};
    const float bv[4] = {b.x, b.y, b.z, b.w};
#pragma unroll
    for (int u = 0; u < 4; ++u) {
      As[(lk + u) * 68 + lrow] = av[u];
      Bs[(lk + u) * 68 + lrow] = bv[u];
    }
    __syncthreads();
#pragma unroll
    for (int k = 0; k < 16; ++k) {
      const float4 a4 = *(const float4*)&As[k * 68 + ty * 4];
      const float4 b4 = *(const float4*)&Bs[k * 68 + tx * 4];
      const float aa[4] = {a4.x, a4.y, a4.z, a4.w};
      const float bb[4] = {b4.x, b4.y, b4.z, b4.w};
#pragma unroll
      for (int i = 0; i < 4; ++i)
#pragma unroll
        for (int j = 0; j < 4; ++j) acc[i][j] += aa[i] * bb[j];
    }
  }
  const int jc = n0 + tx * 4;
  if (jc < G4H) {
    float bs[4];
#pragma unroll
    for (int u = 0; u < 4; ++u) bs[u] = bih[jc + u] + bhh[jc + u];
#pragma unroll
    for (int i = 0; i < 4; ++i) {
      const size_t m = (size_t)m0 + ty * 4 + i;
      const float4 v = make_float4(acc[i][0] + bs[0], acc[i][1] + bs[1],
                                   acc[i][2] + bs[2], acc[i][3] + bs[3]);
      *(float4*)(G + m * G4H + jc) = v;
    }
  }
}

// ---------------------------------------------------------------------------
// Recurrence: one block (512 thr) per 2 batch elements; 128 blocks.
// GEMV weight streams use dwordx4 loads (lane owns 4 output columns).
// waves_per_eu pinned to (2,2): LDS already caps at 1 block/CU (= 2 waves/EU)
// so this costs no occupancy and unlocks the 256-VGPR budget for PIPE4.
// ---------------------------------------------------------------------------
__global__
__attribute__((amdgpu_flat_work_group_size(512, 512), amdgpu_waves_per_eu(2, 2)))
void mann_kernel(
    const float* __restrict__ G, const float* __restrict__ WhhT,
    const float* __restrict__ WrhT, const float* __restrict__ WkaT,
    const float* __restrict__ bka, const float* __restrict__ brh,
    const float* __restrict__ Who, const float* __restrict__ bho,
    const float* __restrict__ Wro, const float* __restrict__ bro,
    float* __restrict__ out)
{
  __shared__ __attribute__((aligned(16))) float M_s[NBAT][NN * MST];
  __shared__ __attribute__((aligned(16))) float h2[HH * NBAT];   // [k*2+i]
  __shared__ __attribute__((aligned(16))) float c2[HH * NBAT];
  __shared__ __attribute__((aligned(16))) float r2[RR * DD * NBAT];
  __shared__ __attribute__((aligned(16))) float brh_s[HH];
  __shared__ float wr_s[NBAT][RR * NN];
  __shared__ float ww_s[NBAT][RR * NN];
  __shared__ float wu_s[NBAT][NN];
  __shared__ float Mn2_s[NBAT][NN];
  __shared__ float kn2_s[NBAT][RR];
  __shared__ __attribute__((aligned(16))) float gates_s[NBAT][G4H];
  __shared__ __attribute__((aligned(16))) float ka_s[NBAT][KAW];
  __shared__ __attribute__((aligned(16))) float bka_s[KAW];
  __shared__ __attribute__((aligned(16))) float Gbuf_s[NBAT][G4H];
  __shared__ float Who_s[NCLS * HH], Wro_s[NCLS * RR * DD], bo_s[NCLS];
  __shared__ int   lu_s[NBAT][RR];

  // Aliases into the gates region (temporally disjoint):
  float*  Kp   = &gates_s[0][0];          // [2][512] wr_t (P8..P12)
  float4* pkA4 = (float4*)&gates_s[0][0]; // P1 partials batch0 (50 float4)
  float4* pkB4 = pkA4 + 50;               // P1 partials batch1
  float4* pka4 = (float4*)&gates_s[0][0]; // P4 partials: [0..80]=b0, [81..161]=b1

  const int tid = threadIdx.x;
  const int b0  = blockIdx.x * NBAT;

  // ---- init ----
  for (int e = tid; e < NBAT * NN * MST; e += 512) (&M_s[0][0])[e] = 0.f;
  for (int e = tid; e < NBAT * RR * NN; e += 512) (&wr_s[0][0])[e] = 0.f;
  if (tid < NBAT * NN) (&wu_s[0][0])[tid] = 0.f;
  for (int e = tid; e < HH * NBAT; e += 512) { h2[e] = 0.f; c2[e] = 0.f; }
  if (tid < RR * DD * NBAT) r2[tid] = 0.f;
  if (tid < HH) brh_s[tid] = brh[tid];
  if (tid < KAW) bka_s[tid] = bka[tid];
  for (int e = tid; e < NCLS * HH; e += 512) Who_s[e] = Who[e];
  for (int e = tid; e < NCLS * RR * DD; e += 512) Wro_s[e] = Wro[e];
  if (tid < NCLS) bo_s[tid] = bho[tid] + bro[tid];
  if (tid < NBAT * 200) {
    const int i = tid / 200, o = tid - i * 200;
    ((float4*)&Gbuf_s[i][0])[o] =
        ((const float4*)(G + ((size_t)(b0 + i) * TB) * G4H))[o];
  }
  __syncthreads();

  const int ofs1 = (int)((blockIdx.x * 3u) % 10u);
  const int ofs2 = (int)((blockIdx.x * 7u) % 25u);
  const int ofs4 = (int)((blockIdx.x * 5u) % 25u);

#pragma clang loop unroll(disable)
  for (int t = 0; t < TB; ++t) {
    float4 a0v = make_float4(0.f, 0.f, 0.f, 0.f);
    float4 a1v = make_float4(0.f, 0.f, 0.f, 0.f);

    // ---- P1: h += r @ Wrh^T + brh (100 lanes: 50 j4 x 2 k-halves, dwordx4) ----
    if (tid < 100) {
      const int kh = tid / 50, j4 = tid - kh * 50;
      const int kbeg = kh * 80;
      const float4* __restrict__ Wr4 = (const float4*)WrhT + (size_t)kbeg * 50 + j4;
      float4 w0[8], w1[8], w2[8], w3[8];
#define P1_LOAD(B, CH) { const int mm = (CH) * 8; _Pragma("unroll") \
      for (int u = 0; u < 8; ++u) B[u] = Wr4[(mm + u) * 50]; }
#define P1_FMA(B, CH) { const int kb = kbeg + (CH) * 8; _Pragma("unroll") \
      for (int u = 0; u < 8; ++u) { const float2 rk = *(const float2*)&r2[(kb + u) * 2]; \
        a0v.x += rk.x * B[u].x; a0v.y += rk.x * B[u].y; a0v.z += rk.x * B[u].z; a0v.w += rk.x * B[u].w; \
        a1v.x += rk.y * B[u].x; a1v.y += rk.y * B[u].y; a1v.z += rk.y * B[u].z; a1v.w += rk.y * B[u].w; } }
      PIPE4(10, ofs1, P1_LOAD, P1_FMA)
      if (kh) { pkA4[j4] = a0v; pkB4[j4] = a1v; }
    }
    __syncthreads();
    if (tid < 50) {
      const int j4 = tid;
      const float4 pA = pkA4[j4], pB = pkB4[j4];
      const float4 brv = ((const float4*)brh_s)[j4];
      float4 hv0 = *(const float4*)&h2[8 * j4];
      float4 hv1 = *(const float4*)&h2[8 * j4 + 4];
      hv0.x += brv.x + a0v.x + pA.x;  hv0.y += brv.x + a1v.x + pB.x;
      hv0.z += brv.y + a0v.y + pA.y;  hv0.w += brv.y + a1v.y + pB.y;
      hv1.x += brv.z + a0v.z + pA.z;  hv1.y += brv.z + a1v.z + pB.z;
      hv1.z += brv.w + a0v.w + pA.w;  hv1.w += brv.w + a1v.w + pB.w;
      *(float4*)&h2[8 * j4]     = hv0;
      *(float4*)&h2[8 * j4 + 4] = hv1;
    }
    __syncthreads();

    // ---- P2: gates = Gbuf + h @ Whh^T (200 lanes x dwordx4, 2 batches) ----
    if (tid < 200) {
      const float4* __restrict__ Wh4 = (const float4*)WhhT + tid;
      float4 g0 = *(const float4*)&Gbuf_s[0][4 * tid];
      float4 g1 = *(const float4*)&Gbuf_s[1][4 * tid];
      float4 w0[8], w1[8], w2[8], w3[8];
#define P2_LOAD(B, CH) { const int kk = (CH) * 8; _Pragma("unroll") \
      for (int u = 0; u < 8; ++u) B[u] = Wh4[(kk + u) * 200]; }
#define P2_FMA(B, CH) { const int kc = (CH) * 8; _Pragma("unroll") \
      for (int u = 0; u < 8; ++u) { const float2 hk = *(const float2*)&h2[(kc + u) * 2]; \
        g0.x += hk.x * B[u].x; g0.y += hk.x * B[u].y; g0.z += hk.x * B[u].z; g0.w += hk.x * B[u].w; \
        g1.x += hk.y * B[u].x; g1.y += hk.y * B[u].y; g1.z += hk.y * B[u].z; g1.w += hk.y * B[u].w; } }
      PIPE4(25, ofs2, P2_LOAD, P2_FMA)
      *(float4*)&gates_s[0][4 * tid] = g0;
      *(float4*)&gates_s[1][4 * tid] = g1;
    }
    __syncthreads();

    // ---- P3: LSTM pointwise (400 items) ----
    if (tid < NBAT * HH) {
      const int i = tid / HH, k = tid - i * HH;
      const float ig = sigmoidf_(gates_s[i][k]);
      const float fg = sigmoidf_(gates_s[i][HH + k]);
      const float gg = tanhf(gates_s[i][2 * HH + k]);
      const float og = sigmoidf_(gates_s[i][3 * HH + k]);
      const float cn = fg * c2[k * NBAT + i] + ig * gg;
      c2[k * NBAT + i] = cn;
      h2[k * NBAT + i] = og * tanhf(cn);
    }
    __syncthreads();

    // ---- P4: [key|add|sigma] = bka + h @ Wka^T (162 lanes x dwordx4) ;
    //      lanes>=384 prefetch G(t+1) ----
    float4 kav0 = make_float4(0.f, 0.f, 0.f, 0.f);
    float4 kav1 = make_float4(0.f, 0.f, 0.f, 0.f);
    if (tid < 162) {
      const int kh = tid / 81, j4 = tid - kh * 81;
      const int kbeg = kh * 100;
      const float4* __restrict__ Wk4 = (const float4*)WkaT + (size_t)kbeg * 81 + j4;
      float4 w0[4], w1[4], w2[4], w3[4];
#define P4_LOAD(B, CH) { const int kk = (CH) * 4; _Pragma("unroll") \
      for (int u = 0; u < 4; ++u) B[u] = Wk4[(kk + u) * 81]; }
#define P4_FMA(B, CH) { const int kc = kbeg + (CH) * 4; _Pragma("unroll") \
      for (int u = 0; u < 4; ++u) { const float2 hk = *(const float2*)&h2[(kc + u) * 2]; \
        kav0.x += hk.x * B[u].x; kav0.y += hk.x * B[u].y; kav0.z += hk.x * B[u].z; kav0.w += hk.x * B[u].w; \
        kav1.x += hk.y * B[u].x; kav1.y += hk.y * B[u].y; kav1.z += hk.y * B[u].z; kav1.w += hk.y * B[u].w; } }
      PIPE4(25, ofs4, P4_LOAD, P4_FMA)
      if (kh) { pka4[j4] = kav0; pka4[81 + j4] = kav1; }
    } else if (tid >= 384 && t + 1 < TB) {
      for (int idx = tid - 384; idx < NBAT * 200; idx += 128) {
        const int i = idx / 200, o = idx - i * 200;
        ((float4*)&Gbuf_s[i][0])[o] =
            ((const float4*)(G + ((size_t)(b0 + i) * TB + t + 1) * G4H))[o];
      }
    }
    __syncthreads();
    if (tid < 81) {
      const float4 bbv = ((const float4*)bka_s)[tid];
      const float4 p0 = pka4[tid], p1 = pka4[81 + tid];
      float4 v0, v1;
      v0.x = kav0.x + p0.x + bbv.x; v0.y = kav0.y + p0.y + bbv.y;
      v0.z = kav0.z + p0.z + bbv.z; v0.w = kav0.w + p0.w + bbv.w;
      v1.x = kav1.x + p1.x + bbv.x; v1.y = kav1.y + p1.y + bbv.y;
      v1.z = kav1.z + p1.z + bbv.z; v1.w = kav1.w + p1.w + bbv.w;
      *(float4*)&ka_s[0][4 * tid] = v0;
      *(float4*)&ka_s[1][4 * tid] = v1;
    }
    __syncthreads();

    // ---- P5: least-used select (waves 0-1, one per batch) + key norms ----
    if (tid < NBAT * 64) {
      const int i = tid >> 6, l = tid & 63;
      unsigned u0v = __float_as_uint(wu_s[i][l]);
      unsigned u1v = __float_as_uint(wu_s[i][l + 64]);
      if (u0v == 0x80000000u) u0v = 0u;
      if (u1v == 0x80000000u) u1v = 0u;
      u0v = (u0v & 0x80000000u) ? ~u0v : (u0v | 0x80000000u);
      u1v = (u1v & 0x80000000u) ? ~u1v : (u1v | 0x80000000u);
      unsigned long long k0 = ((unsigned long long)u0v << 32) | (unsigned)l;
      unsigned long long k1 = ((unsigned long long)u1v << 32) | (unsigned)(l + 64);
#pragma unroll
      for (int rsel = 0; rsel < RR; ++rsel) {
        unsigned long long mn = (k0 < k1) ? k0 : k1;
#pragma unroll
        for (int off = 32; off; off >>= 1) {
          const unsigned long long o = __shfl_xor(mn, off);
          if (o < mn) mn = o;
        }
        const int idx = (int)(mn & 0xFFFFFFFFull);
        if (l == 0) lu_s[i][rsel] = idx;
        if (idx == l)      k0 = ~0ull;
        if (idx == l + 64) k1 = ~0ull;
      }
    } else if (tid < NBAT * 64 + NBAT * RR) {
      const int e = tid - NBAT * 64;
      const int i = e >> 2, q = e & 3;
      float s = 0.f;
#pragma unroll
      for (int d4 = 0; d4 < 10; ++d4) {
        const float4 v = *(const float4*)&ka_s[i][q * DD + 4 * d4];
        s += v.x * v.x + v.y * v.y + v.z * v.z + v.w * v.w;
      }
      kn2_s[i][q] = s;
    }
    __syncthreads();

    // ---- P6: ww = sigma*wr + (1-sigma)*wlu ----
    {
      const int n = tid & (NN - 1);
#pragma unroll
      for (int i = 0; i < NBAT; ++i) {
        const float sg = ka_s[i][320];
        const int l0 = lu_s[i][0], l1 = lu_s[i][1], l2 = lu_s[i][2], l3 = lu_s[i][3];
        const float wlu = (n == l0 || n == l1 || n == l2 || n == l3) ? 1.f : 0.f;
        ww_s[i][tid] = sg * wr_s[i][tid] + (1.f - sg) * wlu;
      }
    }
    __syncthreads();

    // ---- P7: M = M*wlu + ww^T @ add ; fused row-norm (256 lanes: i,n) ----
    if (tid < NBAT * NN) {
      const int i = tid >> 7, n = tid & (NN - 1);
      const int l0 = lu_s[i][0], l1 = lu_s[i][1], l2 = lu_s[i][2], l3 = lu_s[i][3];
      const float wlu = (n == l0 || n == l1 || n == l2 || n == l3) ? 1.f : 0.f;
      const float wwv0 = ww_s[i][n],          wwv1 = ww_s[i][NN + n];
      const float wwv2 = ww_s[i][2 * NN + n], wwv3 = ww_s[i][3 * NN + n];
      float* Mr = &M_s[i][n * MST];
      const float* Ad = &ka_s[i][160];
      float mn2 = 0.f;
#pragma unroll
      for (int d4 = 0; d4 < 10; ++d4) {
        float4 m = *(const float4*)&Mr[4 * d4];
        m.x *= wlu; m.y *= wlu; m.z *= wlu; m.w *= wlu;
        const float4 av0 = *(const float4*)&Ad[0 * DD + 4 * d4];
        const float4 av1 = *(const float4*)&Ad[1 * DD + 4 * d4];
        const float4 av2 = *(const float4*)&Ad[2 * DD + 4 * d4];
        const float4 av3 = *(const float4*)&Ad[3 * DD + 4 * d4];
        m.x += wwv0 * av0.x + wwv1 * av1.x + wwv2 * av2.x + wwv3 * av3.x;
        m.y += wwv0 * av0.y + wwv1 * av1.y + wwv2 * av2.y + wwv3 * av3.y;
        m.z += wwv0 * av0.z + wwv1 * av1.z + wwv2 * av2.z + wwv3 * av3.z;
        m.w += wwv0 * av0.w + wwv1 * av1.w + wwv2 * av2.w + wwv3 * av3.w;
        *(float4*)&Mr[4 * d4] = m;
        mn2 += m.x * m.x + m.y * m.y + m.z * m.z + m.w * m.w;
      }
      Mn2_s[i][n] = mn2;
    }
    __syncthreads();

    // ---- P8: K = cosine(key, M): 512 lanes, each reads one M row, 2 keys ----
    {
      const int i = tid >> 8, qq = (tid >> 7) & 1, n = tid & (NN - 1);
      const float* Mr = &M_s[i][n * MST];
      const float* Ky0 = &ka_s[i][qq * DD];
      const float* Ky1 = &ka_s[i][(qq + 2) * DD];
      float s0 = 0.f, s1 = 0.f;
#pragma unroll
      for (int d4 = 0; d4 < 10; ++d4) {
        const float4 mv = *(const float4*)&Mr[4 * d4];
        const float4 k0v = *(const float4*)&Ky0[4 * d4];
        const float4 k1v = *(const float4*)&Ky1[4 * d4];
        s0 += k0v.x * mv.x + k0v.y * mv.y + k0v.z * mv.z + k0v.w * mv.w;
        s1 += k1v.x * mv.x + k1v.y * mv.y + k1v.z * mv.z + k1v.w * mv.w;
      }
      const float mn2 = Mn2_s[i][n];
      Kp[(i << 9) + qq * NN + n]       = s0 / sqrtf(kn2_s[i][qq] * mn2 + 1e-6f);
      Kp[(i << 9) + (qq + 2) * NN + n] = s1 / sqrtf(kn2_s[i][qq + 2] * mn2 + 1e-6f);
    }
    __syncthreads();

    // ---- P9: softmax over N (8 rows, one per wave) ----
    {
      const int w = tid >> 6, l = tid & 63;
      float* Kr = Kp + ((w >> 2) << 9) + (w & 3) * NN;
      const float v0 = Kr[l], v1 = Kr[l + 64];
      float mx = fmaxf(v0, v1);
#pragma unroll
      for (int off = 32; off; off >>= 1) mx = fmaxf(mx, __shfl_xor(mx, off));
      const float e0 = expf(v0 - mx), e1 = expf(v1 - mx);
      float s = e0 + e1;
#pragma unroll
      for (int off = 32; off; off >>= 1) s += __shfl_xor(s, off);
      const float inv = 1.f / s;
      Kr[l] = e0 * inv; Kr[l + 64] = e1 * inv;
    }
    __syncthreads();

    // ---- P10: r = wr_t @ M (80 lanes, broadcast) ; P11: wu (lanes 256+) ----
    if (tid < NBAT * RR * 10) {
      const int i = tid / (RR * 10), rem = tid - i * (RR * 10);
      const int q = rem / 10, d4 = rem - q * 10;
      const float* Kr = Kp + (i << 9) + q * NN;
      const float* Mb = &M_s[i][4 * d4];
      float4 acc = make_float4(0.f, 0.f, 0.f, 0.f);
      for (int n = 0; n < NN; ++n) {
        const float kw = Kr[n];
        const float4 mv = *(const float4*)&Mb[n * MST];
        acc.x += kw * mv.x; acc.y += kw * mv.y;
        acc.z += kw * mv.z; acc.w += kw * mv.w;
      }
      const int dbase = (q * DD + 4 * d4) * NBAT + i;
      r2[dbase]            = acc.x;
      r2[dbase + NBAT]     = acc.y;
      r2[dbase + 2 * NBAT] = acc.z;
      r2[dbase + 3 * NBAT] = acc.w;
    } else if (tid >= 256 && tid < 256 + NBAT * NN) {
      const int e = tid - 256;
      const int i = e >> 7, n = e & (NN - 1);
      float s = 0.95f * wu_s[i][n];
#pragma unroll
      for (int q = 0; q < RR; ++q)
        s += Kp[(i << 9) + q * NN + n] + ww_s[i][q * NN + n];
      wu_s[i][n] = s;
    }
    __syncthreads();

    // ---- P12: out (waves 0-1) ; wr <- wr_t (waves 4-7) ----
    if (tid < NBAT * 64) {
      const int i = tid >> 6, l = tid & 63;
      const size_t ob = ((size_t)(b0 + i) * TB + t) * NCLS;
#pragma unroll
      for (int j = 0; j < NCLS; ++j) {
        float p = 0.f;
        for (int k = l; k < HH; k += 64)      p += h2[k * NBAT + i] * Who_s[j * HH + k];
        for (int m = l; m < RR * DD; m += 64) p += r2[m * NBAT + i] * Wro_s[j * RR * DD + m];
#pragma unroll
        for (int off = 32; off; off >>= 1) p += __shfl_xor(p, off);
        if (l == 0) out[ob + j] = p + bo_s[j];
      }
    } else if (tid >= 256) {
      for (int f = tid - 256; f < NBAT * RR * NN; f += 256) (&wr_s[0][0])[f] = Kp[f];
    }
    __syncthreads();
  }
}

// ---------------------------------------------------------------------------
extern "C" void kernel_launch(void* const* d_in, const int* in_sizes, int n_in,
                              void* d_out, int out_size, void* d_ws, size_t ws_size,
                              hipStream_t stream) {
  const float* x    = (const float*)d_in[0];
  const float* Wkey = (const float*)d_in[1];
  const float* bkey = (const float*)d_in[2];
  const float* Wadd = (const float*)d_in[3];
  const float* badd = (const float*)d_in[4];
  const float* Wsig = (const float*)d_in[5];
  const float* bsig = (const float*)d_in[6];
  const float* Who  = (const float*)d_in[7];
  const float* bho  = (const float*)d_in[8];
  const float* Wro  = (const float*)d_in[9];
  const float* bro  = (const float*)d_in[10];
  const float* Wrh  = (const float*)d_in[11];
  const float* brh  = (const float*)d_in[12];
  const float* Wih  = (const float*)d_in[13];
  const float* bih  = (const float*)d_in[14];
  const float* Whh  = (const float*)d_in[15];
  const float* bhh  = (const float*)d_in[16];

  float* ws   = (float*)d_ws;
  float* G    = ws;                       // 25600*800
  float* WhhT = G + (size_t)25600 * 800;  // 160,000
  float* WrhT = WhhT + 160000;            // 32,000
  float* WkaT = WrhT + 32000;             // 64,800
  float* bka  = WkaT + 64800;             // 324

  prep_kernel<<<(160000 + 255) / 256, 256, 0, stream>>>(
      Whh, Wrh, Wkey, Wadd, Wsig, bkey, badd, bsig, WhhT, WrhT, WkaT, bka);

  dim3 gA((G4H + 63) / 64, 25600 / 64);
  gemm_in_kernel<<<gA, 256, 0, stream>>>(x, Wih, bih, bhh, G);

  mann_kernel<<<NBLK, 512, 0, stream>>>(G, WhhT, WrhT, WkaT, bka, brh,
                                        Who, bho, Wro, bro, (float*)d_out);
}